// Round 1
// baseline (9110.999 us; speedup 1.0000x reference)
//
#include <hip/hip_runtime.h>
#include <math.h>

#define NN 8192
#define DD 2048
#define KK 256

// ---------- block reduce (256 threads, wave=64) ----------
__device__ __forceinline__ float blockReduceSum(float val, float* sdata) {
    for (int off = 32; off > 0; off >>= 1)
        val += __shfl_down(val, off, 64);
    int wid = threadIdx.x >> 6;
    int lane = threadIdx.x & 63;
    __syncthreads();                 // protect sdata reads from a previous call
    if (lane == 0) sdata[wid] = val;
    __syncthreads();
    return sdata[0] + sdata[1] + sdata[2] + sdata[3];
}

// ---------- V0 [D][K] -> V0T [K][D] ----------
__global__ void ktranspose(const float* __restrict__ V0, float* __restrict__ V0T) {
    __shared__ float tile[32][33];
    int bx = blockIdx.x;             // D / 32 tiles
    int by = blockIdx.y;             // K / 32 tiles
    int tx = threadIdx.x % 32;
    int ty = threadIdx.x / 32;       // 0..7
    for (int r = ty; r < 32; r += 8)
        tile[r][tx] = V0[(size_t)(bx * 32 + r) * KK + by * 32 + tx];
    __syncthreads();
    for (int r = ty; r < 32; r += 8)
        V0T[(size_t)(by * 32 + r) * DD + bx * 32 + tx] = tile[tx][r];
}

// ---------- d0[k] = ||V0[:,k]|| ----------
__global__ void kd0(const float* __restrict__ V0T, float* __restrict__ d0) {
    __shared__ float sdata[4];
    int k = blockIdx.x;
    float acc = 0.f;
    for (int j = threadIdx.x; j < DD; j += 256) {
        float v = V0T[(size_t)k * DD + j];
        acc += v * v;
    }
    float s = blockReduceSum(acc, sdata);
    if (threadIdx.x == 0) d0[k] = sqrtf(s);
}

// ---------- p[i] = r[i,:] . v  (one block per row) ----------
__global__ void kmatvec_rows(const float* __restrict__ r, const float* __restrict__ v,
                             float* __restrict__ p) {
    __shared__ float sdata[4];
    int i = blockIdx.x;
    const float* row = r + (size_t)i * DD;
    float acc = 0.f;
    for (int j = threadIdx.x; j < DD; j += 256)
        acc += row[j] * v[j];
    float s = blockReduceSum(acc, sdata);
    if (threadIdx.x == 0) p[i] = s;
}

// ---------- s[c] += sum_i r[i,c] * p[i]  (column-parallel, coalesced) ----------
__global__ void kATp(const float* __restrict__ r, const float* __restrict__ p,
                     float* __restrict__ s) {
    int c = blockIdx.x * 256 + threadIdx.x;        // 8 blocks in x cover D
    int i0 = blockIdx.y * (NN / 64);               // 64 row chunks of 128 rows
    float acc = 0.f;
    for (int i = i0; i < i0 + NN / 64; ++i)
        acc += r[(size_t)i * DD + c] * p[i];
    atomicAdd(&s[c], acc);
}

// ---------- u = 0.5 v + (0.5/d) s ; vn = u/||u|| -> Vn row k ; zero s ----------
__global__ void kupdate_v(const float* __restrict__ V0T, const float* __restrict__ d0,
                          float* __restrict__ s, float* __restrict__ Vn, int k) {
    __shared__ float sdata[4];
    float u[8];
    float c = 0.5f / d0[k];
    const float* v = V0T + (size_t)k * DD;
    float acc = 0.f;
    for (int t = 0; t < 8; ++t) {
        int j = threadIdx.x + t * 256;
        float uj = 0.5f * v[j] + c * s[j];
        u[t] = uj;
        acc += uj * uj;
        s[j] = 0.f;                                // ready for next iteration's atomics
    }
    float dn = blockReduceSum(acc, sdata);
    float inv = 1.0f / sqrtf(dn);
    for (int t = 0; t < 8; ++t) {
        int j = threadIdx.x + t * 256;
        Vn[(size_t)k * DD + j] = u[t] * inv;
    }
}

// ---------- q = r[i,:].vn ; r[i,:] -= q vn ; p[i] = r_new[i,:].vnext ----------
__global__ void kdeflate(float* __restrict__ r, const float* __restrict__ vn,
                         const float* __restrict__ vnext, float* __restrict__ p) {
    __shared__ float sdata[4];
    int i = blockIdx.x;
    float* row = r + (size_t)i * DD;
    float rv[8], vv[8];
    float acc = 0.f;
    for (int t = 0; t < 8; ++t) {
        int j = threadIdx.x + t * 256;
        rv[t] = row[j];
        vv[t] = vn[j];
        acc += rv[t] * vv[t];
    }
    float q = blockReduceSum(acc, sdata);
    float acc2 = 0.f;
    for (int t = 0; t < 8; ++t) {
        int j = threadIdx.x + t * 256;
        float nv = rv[t] - q * vv[t];
        row[j] = nv;
        acc2 += nv * vnext[j];
    }
    float s2 = blockReduceSum(acc2, sdata);
    if (threadIdx.x == 0) p[i] = s2;
}

// ---------- out[N][K] = x . Vn^T  (64x64 tiles, fp32) ----------
__global__ void kout(const float* __restrict__ x, const float* __restrict__ Vn,
                     float* __restrict__ out) {
    __shared__ float As[32][68];
    __shared__ float Bs[32][68];
    int i0 = blockIdx.x * 64;
    int k0 = blockIdx.y * 64;
    int tid = threadIdx.x;
    int tr = tid / 16;        // 0..15 -> 4 rows each
    int tc = tid % 16;        // 0..15 -> 4 cols each
    float acc[4][4] = {};
    for (int j0 = 0; j0 < DD; j0 += 32) {
        int c = tid % 32;
        int r0 = tid / 32;    // 0..7
        for (int pass = 0; pass < 8; ++pass) {
            int rr = r0 + pass * 8;
            As[c][rr] = x[(size_t)(i0 + rr) * DD + j0 + c];
            Bs[c][rr] = Vn[(size_t)(k0 + rr) * DD + j0 + c];
        }
        __syncthreads();
        for (int kk = 0; kk < 32; ++kk) {
            float4 a4 = *(const float4*)&As[kk][tr * 4];
            float4 b4 = *(const float4*)&Bs[kk][tc * 4];
            float a[4] = {a4.x, a4.y, a4.z, a4.w};
            float b[4] = {b4.x, b4.y, b4.z, b4.w};
            for (int ar = 0; ar < 4; ++ar)
                for (int bc = 0; bc < 4; ++bc)
                    acc[ar][bc] += a[ar] * b[bc];
        }
        __syncthreads();
    }
    for (int ar = 0; ar < 4; ++ar) {
        float4 o = make_float4(acc[ar][0], acc[ar][1], acc[ar][2], acc[ar][3]);
        *(float4*)&out[(size_t)(i0 + tr * 4 + ar) * KK + k0 + tc * 4] = o;
    }
}

extern "C" void kernel_launch(void* const* d_in, const int* in_sizes, int n_in,
                              void* d_out, int out_size, void* d_ws, size_t ws_size,
                              hipStream_t stream) {
    const float* x  = (const float*)d_in[0];   // [N*D]
    const float* V0 = (const float*)d_in[1];   // [D*K]
    float* out = (float*)d_out;                // [N*K]

    float* r   = (float*)d_ws;                 // N*D
    float* p   = r + (size_t)NN * DD;          // N
    float* s   = p + NN;                       // D
    float* Vn  = s + DD;                       // K*D
    float* V0T = Vn + (size_t)KK * DD;         // K*D
    float* d0  = V0T + (size_t)KK * DD;        // K

    // r = x (residual working copy); s = 0 (atomic accumulator)
    hipMemcpyAsync(r, x, (size_t)NN * DD * sizeof(float), hipMemcpyDeviceToDevice, stream);
    hipMemsetAsync(s, 0, DD * sizeof(float), stream);

    ktranspose<<<dim3(DD / 32, KK / 32), 256, 0, stream>>>(V0, V0T);
    kd0<<<KK, 256, 0, stream>>>(V0T, d0);

    // initial p = r @ v_0
    kmatvec_rows<<<NN, 256, 0, stream>>>(r, V0T, p);

    for (int k = 0; k < KK; ++k) {
        kATp<<<dim3(DD / 256, 64), 256, 0, stream>>>(r, p, s);
        kupdate_v<<<1, 256, 0, stream>>>(V0T, d0, s, Vn, k);
        if (k < KK - 1) {
            kdeflate<<<NN, 256, 0, stream>>>(r, Vn + (size_t)k * DD,
                                             V0T + (size_t)(k + 1) * DD, p);
        }
    }

    kout<<<dim3(NN / 64, KK / 64), 256, 0, stream>>>(x, Vn, out);
}

// Round 2
// 3620.519 us; speedup vs baseline: 2.5165x; 2.5165x over previous
//
#include <hip/hip_runtime.h>
#include <math.h>

#define NN 8192
#define DD 2048
#define KK 256

// ---------- block reduce (256 threads, wave=64) ----------
__device__ __forceinline__ float blockReduceSum(float val, float* sdata) {
    for (int off = 32; off > 0; off >>= 1)
        val += __shfl_down(val, off, 64);
    int wid = threadIdx.x >> 6;
    int lane = threadIdx.x & 63;
    __syncthreads();
    if (lane == 0) sdata[wid] = val;
    __syncthreads();
    return sdata[0] + sdata[1] + sdata[2] + sdata[3];
}

// ---------- V0 [D][K] -> V0T [K][D] ----------
__global__ void ktranspose(const float* __restrict__ V0, float* __restrict__ V0T) {
    __shared__ float tile[32][33];
    int bx = blockIdx.x;             // D / 32 tiles
    int by = blockIdx.y;             // K / 32 tiles
    int tx = threadIdx.x % 32;
    int ty = threadIdx.x / 32;       // 0..7
    for (int r = ty; r < 32; r += 8)
        tile[r][tx] = V0[(size_t)(bx * 32 + r) * KK + by * 32 + tx];
    __syncthreads();
    for (int r = ty; r < 32; r += 8)
        V0T[(size_t)(by * 32 + r) * DD + bx * 32 + tx] = tile[tx][r];
}

// ---------- d0[k] = ||V0[:,k]|| ----------
__global__ void kd0(const float* __restrict__ V0T, float* __restrict__ d0) {
    __shared__ float sdata[4];
    int k = blockIdx.x;
    float acc = 0.f;
    for (int j = threadIdx.x; j < DD; j += 256) {
        float v = V0T[(size_t)k * DD + j];
        acc += v * v;
    }
    float s = blockReduceSum(acc, sdata);
    if (threadIdx.x == 0) d0[k] = sqrtf(s);
}

// ---------- G = x^T x, triangle tiles + inline mirror ----------
__global__ void ksyrk(const float* __restrict__ x, float* __restrict__ G) {
    __shared__ float As[32][68];
    __shared__ float Bs[32][68];
    int t = blockIdx.x;
    // decode t -> (bi, bj) with bi <= bj, t = bj*(bj+1)/2 + bi
    int bj = (int)((sqrtf(8.0f * (float)t + 1.0f) - 1.0f) * 0.5f);
    while ((bj + 1) * (bj + 2) / 2 <= t) ++bj;
    while (bj * (bj + 1) / 2 > t) --bj;
    int bi = t - bj * (bj + 1) / 2;
    int a0 = bi * 64, b0 = bj * 64;
    int tid = threadIdx.x;
    int al = tid % 64;       // column within tile (contiguous in x)
    int nl0 = tid / 64;      // 0..3
    int tr = tid / 16, tc = tid % 16;
    float acc[4][4] = {};
    for (int n0 = 0; n0 < NN; n0 += 32) {
        for (int pass = 0; pass < 8; ++pass) {
            int nl = nl0 + pass * 4;
            As[nl][al] = x[(size_t)(n0 + nl) * DD + a0 + al];
            Bs[nl][al] = x[(size_t)(n0 + nl) * DD + b0 + al];
        }
        __syncthreads();
        for (int kk2 = 0; kk2 < 32; ++kk2) {
            float4 a4 = *(const float4*)&As[kk2][tr * 4];
            float4 b4 = *(const float4*)&Bs[kk2][tc * 4];
            float a[4] = {a4.x, a4.y, a4.z, a4.w};
            float b[4] = {b4.x, b4.y, b4.z, b4.w};
            for (int i = 0; i < 4; ++i)
                for (int j = 0; j < 4; ++j)
                    acc[i][j] += a[i] * b[j];
        }
        __syncthreads();
    }
    for (int i = 0; i < 4; ++i) {
        float4 o = make_float4(acc[i][0], acc[i][1], acc[i][2], acc[i][3]);
        *(float4*)&G[(size_t)(a0 + tr * 4 + i) * DD + b0 + tc * 4] = o;
    }
    if (bi != bj) {
        for (int i = 0; i < 4; ++i)
            for (int j = 0; j < 4; ++j)
                G[(size_t)(b0 + tc * 4 + j) * DD + a0 + tr * 4 + i] = acc[i][j];
    }
}

// ---------- s = G v (512 blocks x 4 rows, wave per row) ----------
__global__ void kmatvecG(const float* __restrict__ G, const float* __restrict__ v,
                         float* __restrict__ s) {
    __shared__ float vs[DD];
    int tid = threadIdx.x;
    for (int t2 = 0; t2 < 8; ++t2) vs[tid + t2 * 256] = v[tid + t2 * 256];
    __syncthreads();
    int wave = tid >> 6, lane = tid & 63;
    int row = blockIdx.x * 4 + wave;
    const float* Gr = G + (size_t)row * DD;
    float a = 0.f;
    for (int c = 0; c < 8; ++c) {
        int idx = lane * 4 + c * 256;
        float4 gq = *(const float4*)(Gr + idx);
        float4 vq = *(const float4*)(vs + idx);
        a += gq.x * vq.x + gq.y * vq.y + gq.z * vq.z + gq.w * vq.w;
    }
    for (int off = 32; off > 0; off >>= 1) a += __shfl_down(a, off, 64);
    if (lane == 0) s[row] = a;
}

// ---------- step1: vn_k from (v_k, d_k, s_k); g = G vn; Vn[k] = vn ----------
__global__ void kstep1(const float* __restrict__ G, const float* __restrict__ V0T,
                       const float* __restrict__ d0, const float* __restrict__ s,
                       float* __restrict__ g, float* __restrict__ Vn, int k) {
    __shared__ float u[DD];
    __shared__ float sdata[4];
    __shared__ float sinv;
    int tid = threadIdx.x;
    const float* v = V0T + (size_t)k * DD;
    float cf = 0.5f / d0[k];
    float acc = 0.f;
    for (int t2 = 0; t2 < 8; ++t2) {
        int j = tid + t2 * 256;
        float uj = 0.5f * v[j] + cf * s[j];
        u[j] = uj;
        acc += uj * uj;
    }
    float n2 = blockReduceSum(acc, sdata);       // barrier also covers u[] writes
    if (tid == 0) sinv = 1.0f / sqrtf(n2);
    __syncthreads();
    float inv = sinv;
    if (blockIdx.x == 0) {
        for (int t2 = 0; t2 < 8; ++t2) {
            int j = tid + t2 * 256;
            Vn[(size_t)k * DD + j] = u[j] * inv;
        }
    }
    int wave = tid >> 6, lane = tid & 63;
    int row = blockIdx.x * 4 + wave;
    const float* Gr = G + (size_t)row * DD;
    float a = 0.f;
    for (int c = 0; c < 8; ++c) {
        int idx = lane * 4 + c * 256;
        float4 gq = *(const float4*)(Gr + idx);
        float4 uq = *(const float4*)(u + idx);
        a += gq.x * uq.x + gq.y * uq.y + gq.z * uq.z + gq.w * uq.w;
    }
    for (int off = 32; off > 0; off >>= 1) a += __shfl_down(a, off, 64);
    if (lane == 0) g[row] = a * inv;             // g = G (u*inv) = G vn
}

// ---------- step2: G -= vn h^T + g vn^T (h = g - c vn); fused s_next = G' v_next ----------
__global__ void kstep2(float* __restrict__ G, const float* __restrict__ V0T,
                       const float* __restrict__ Vn, const float* __restrict__ g,
                       float* __restrict__ s_next, int k, int knext) {
    __shared__ float vn_s[DD];
    __shared__ float h_s[DD];
    __shared__ float w_s[DD];
    __shared__ float sdata[4];
    int tid = threadIdx.x;
    float acc = 0.f;
    for (int t2 = 0; t2 < 8; ++t2) {
        int j = tid + t2 * 256;
        float vnj = Vn[(size_t)k * DD + j];
        float gj = g[j];
        vn_s[j] = vnj;
        h_s[j] = gj;
        w_s[j] = V0T[(size_t)knext * DD + j];
        acc += vnj * gj;
    }
    float c = blockReduceSum(acc, sdata);        // c = vn^T G vn
    for (int t2 = 0; t2 < 8; ++t2) {
        int j = tid + t2 * 256;
        h_s[j] -= c * vn_s[j];
    }
    __syncthreads();
    int wave = tid >> 6, lane = tid & 63;
    int row = blockIdx.x * 4 + wave;
    float vni = vn_s[row], gi = g[row];
    float* Gr = G + (size_t)row * DD;
    float a = 0.f;
    for (int cc = 0; cc < 8; ++cc) {
        int idx = lane * 4 + cc * 256;
        float4 Gq = *(float4*)(Gr + idx);
        float4 hq = *(const float4*)(h_s + idx);
        float4 vq = *(const float4*)(vn_s + idx);
        float4 wq = *(const float4*)(w_s + idx);
        Gq.x = Gq.x - vni * hq.x - gi * vq.x;
        Gq.y = Gq.y - vni * hq.y - gi * vq.y;
        Gq.z = Gq.z - vni * hq.z - gi * vq.z;
        Gq.w = Gq.w - vni * hq.w - gi * vq.w;
        a += Gq.x * wq.x + Gq.y * wq.y + Gq.z * wq.z + Gq.w * wq.w;
        *(float4*)(Gr + idx) = Gq;
    }
    for (int off = 32; off > 0; off >>= 1) a += __shfl_down(a, off, 64);
    if (lane == 0) s_next[row] = a;
}

// ---------- out[N][K] = x . Vn^T  (64x64 tiles, fp32) ----------
__global__ void kout(const float* __restrict__ x, const float* __restrict__ Vn,
                     float* __restrict__ out) {
    __shared__ float As[32][68];
    __shared__ float Bs[32][68];
    int i0 = blockIdx.x * 64;
    int k0 = blockIdx.y * 64;
    int tid = threadIdx.x;
    int tr = tid / 16;
    int tc = tid % 16;
    float acc[4][4] = {};
    for (int j0 = 0; j0 < DD; j0 += 32) {
        int c = tid % 32;
        int r0 = tid / 32;
        for (int pass = 0; pass < 8; ++pass) {
            int rr = r0 + pass * 8;
            As[c][rr] = x[(size_t)(i0 + rr) * DD + j0 + c];
            Bs[c][rr] = Vn[(size_t)(k0 + rr) * DD + j0 + c];
        }
        __syncthreads();
        for (int kk = 0; kk < 32; ++kk) {
            float4 a4 = *(const float4*)&As[kk][tr * 4];
            float4 b4 = *(const float4*)&Bs[kk][tc * 4];
            float a[4] = {a4.x, a4.y, a4.z, a4.w};
            float b[4] = {b4.x, b4.y, b4.z, b4.w};
            for (int ar = 0; ar < 4; ++ar)
                for (int bc = 0; bc < 4; ++bc)
                    acc[ar][bc] += a[ar] * b[bc];
        }
        __syncthreads();
    }
    for (int ar = 0; ar < 4; ++ar) {
        float4 o = make_float4(acc[ar][0], acc[ar][1], acc[ar][2], acc[ar][3]);
        *(float4*)&out[(size_t)(i0 + tr * 4 + ar) * KK + k0 + tc * 4] = o;
    }
}

extern "C" void kernel_launch(void* const* d_in, const int* in_sizes, int n_in,
                              void* d_out, int out_size, void* d_ws, size_t ws_size,
                              hipStream_t stream) {
    const float* x  = (const float*)d_in[0];   // [N*D]
    const float* V0 = (const float*)d_in[1];   // [D*K]
    float* out = (float*)d_out;                // [N*K]

    float* G    = (float*)d_ws;                // D*D
    float* V0T  = G + (size_t)DD * DD;         // K*D
    float* Vn   = V0T + (size_t)KK * DD;       // K*D
    float* g    = Vn + (size_t)KK * DD;        // D
    float* sbuf = g + DD;                      // 2*D (double-buffered s)
    float* d0   = sbuf + 2 * DD;               // K

    ktranspose<<<dim3(DD / 32, KK / 32), 256, 0, stream>>>(V0, V0T);
    kd0<<<KK, 256, 0, stream>>>(V0T, d0);
    ksyrk<<<528, 256, 0, stream>>>(x, G);
    kmatvecG<<<512, 256, 0, stream>>>(G, V0T, sbuf);   // s_0 = G v_0

    for (int k = 0; k < KK; ++k) {
        float* s_cur = sbuf + (k & 1) * DD;
        float* s_nxt = sbuf + ((k + 1) & 1) * DD;
        kstep1<<<512, 256, 0, stream>>>(G, V0T, d0, s_cur, g, Vn, k);
        if (k < KK - 1)
            kstep2<<<512, 256, 0, stream>>>(G, V0T, Vn, g, s_nxt, k, k + 1);
    }

    kout<<<dim3(NN / 64, KK / 64), 256, 0, stream>>>(x, Vn, out);
}